// Round 4
// baseline (83.900 us; speedup 1.0000x reference)
//
#include <hip/hip_runtime.h>
#include <stdint.h>

#define DIMS 96
#define VEC 4
#define LANES (DIMS / VEC)        // 24 lanes cover one 96-dim row as float4
#define SPLIT 2                   // edge-parallel sub-groups per segment
#define GLANES (LANES * SPLIT)    // 48 threads per segment
#define SEGS_PER_BLOCK 8
#define THREADS (GLANES * SEGS_PER_BLOCK)  // 384 threads = 6 waves
#define IDX_CAP 1024              // staged indices per block (avg need ~128)

// Segment-mean aggregation over sorted seg_ids.
// Round-4 changes vs round-3 (latency-bound: VALUBusy 6.6%, HBM 32%):
//  - block's neighbor indices staged in LDS (removes global idx load from
//    the dependent chain)
//  - each segment served by 2 x 24-lane sub-groups over even/odd edges
//    (halves serial chain, doubles gathers in flight), LDS-reduced at end.
// NOTE: harness delivers integer inputs as int32.
__global__ __launch_bounds__(THREADS) void seg_mean_concat_kernel(
    const float* __restrict__ emb,        // [N, 96]
    const float* __restrict__ self_feats, // [B, 96]
    const int*   __restrict__ nidx,       // [E] int32
    const int*   __restrict__ seg,        // [E] int32, sorted
    float* __restrict__ out,              // [B, 192]
    int B, int E)
{
    __shared__ int bounds[SEGS_PER_BLOCK + 1];
    __shared__ int sidx[IDX_CAP];
    __shared__ float4 psum[SEGS_PER_BLOCK][LANES];

    const int b0 = blockIdx.x * SEGS_PER_BLOCK;
    const int tid = threadIdx.x;

    // lower_bound(seg, b0 + t) for t = 0..SEGS_PER_BLOCK
    if (tid <= SEGS_PER_BLOCK) {
        const int v = b0 + tid;
        int lo = 0, hi = E;
        while (lo < hi) {
            int mid = (lo + hi) >> 1;
            if (seg[mid] < v) lo = mid + 1; else hi = mid;
        }
        bounds[tid] = lo;
    }
    __syncthreads();

    const int e0    = bounds[0];
    const int total = bounds[SEGS_PER_BLOCK] - e0;
    const bool staged = (total <= IDX_CAP);   // block-uniform
    if (staged) {
        for (int i = tid; i < total; i += THREADS) sidx[i] = nidx[e0 + i];
    }
    __syncthreads();

    const int g    = tid / GLANES;            // segment group within block
    const int r    = tid - g * GLANES;
    const int sub  = r / LANES;               // 0 or 1: even/odd edges
    const int lane = r - sub * LANES;         // float4 slot within row
    const int b    = b0 + g;
    if (b >= B) return;

    const int start = bounds[g];
    const int end   = bounds[g + 1];

    const float4* __restrict__ embv = (const float4*)emb;

    // issue self_feats load early so it overlaps the gather loop
    float4 sf = make_float4(0.f, 0.f, 0.f, 0.f);
    if (sub == 0) sf = *(const float4*)(self_feats + (size_t)b * DIMS + lane * VEC);

    float4 acc = make_float4(0.f, 0.f, 0.f, 0.f);

    if (staged) {
        const int s1 = end - e0;
        int e = (start - e0) + sub;
        // 8 independent gathers in flight, indices from LDS
        for (; e + 7 * SPLIT < s1; e += 8 * SPLIT) {
            const int j0 = sidx[e + 0 * SPLIT];
            const int j1 = sidx[e + 1 * SPLIT];
            const int j2 = sidx[e + 2 * SPLIT];
            const int j3 = sidx[e + 3 * SPLIT];
            const int j4 = sidx[e + 4 * SPLIT];
            const int j5 = sidx[e + 5 * SPLIT];
            const int j6 = sidx[e + 6 * SPLIT];
            const int j7 = sidx[e + 7 * SPLIT];
            const float4 v0 = embv[(size_t)j0 * LANES + lane];
            const float4 v1 = embv[(size_t)j1 * LANES + lane];
            const float4 v2 = embv[(size_t)j2 * LANES + lane];
            const float4 v3 = embv[(size_t)j3 * LANES + lane];
            const float4 v4 = embv[(size_t)j4 * LANES + lane];
            const float4 v5 = embv[(size_t)j5 * LANES + lane];
            const float4 v6 = embv[(size_t)j6 * LANES + lane];
            const float4 v7 = embv[(size_t)j7 * LANES + lane];
            acc.x += v0.x + v1.x + v2.x + v3.x + v4.x + v5.x + v6.x + v7.x;
            acc.y += v0.y + v1.y + v2.y + v3.y + v4.y + v5.y + v6.y + v7.y;
            acc.z += v0.z + v1.z + v2.z + v3.z + v4.z + v5.z + v6.z + v7.z;
            acc.w += v0.w + v1.w + v2.w + v3.w + v4.w + v5.w + v6.w + v7.w;
        }
        // 4-deep tier for medium tails
        for (; e + 3 * SPLIT < s1; e += 4 * SPLIT) {
            const int j0 = sidx[e + 0 * SPLIT];
            const int j1 = sidx[e + 1 * SPLIT];
            const int j2 = sidx[e + 2 * SPLIT];
            const int j3 = sidx[e + 3 * SPLIT];
            const float4 v0 = embv[(size_t)j0 * LANES + lane];
            const float4 v1 = embv[(size_t)j1 * LANES + lane];
            const float4 v2 = embv[(size_t)j2 * LANES + lane];
            const float4 v3 = embv[(size_t)j3 * LANES + lane];
            acc.x += v0.x + v1.x + v2.x + v3.x;
            acc.y += v0.y + v1.y + v2.y + v3.y;
            acc.z += v0.z + v1.z + v2.z + v3.z;
            acc.w += v0.w + v1.w + v2.w + v3.w;
        }
        for (; e < s1; e += SPLIT) {
            const int j = sidx[e];
            const float4 v = embv[(size_t)j * LANES + lane];
            acc.x += v.x; acc.y += v.y; acc.z += v.z; acc.w += v.w;
        }
    } else {
        // overflow fallback (practically never taken): read indices from global
        for (int e = start + sub; e < end; e += SPLIT) {
            const int j = nidx[e];
            const float4 v = embv[(size_t)j * LANES + lane];
            acc.x += v.x; acc.y += v.y; acc.z += v.z; acc.w += v.w;
        }
    }

    // reduce the two sub-group partials via LDS
    if (sub == 1) psum[g][lane] = acc;
    __syncthreads();
    if (sub != 0) return;

    const float4 p = psum[g][lane];
    acc.x += p.x; acc.y += p.y; acc.z += p.z; acc.w += p.w;

    const int cnt = end - start;
    const float inv = 1.0f / (float)(cnt > 0 ? cnt : 1);
    float4 mean;
    mean.x = acc.x * inv; mean.y = acc.y * inv;
    mean.z = acc.z * inv; mean.w = acc.w * inv;

    float4 diff;
    diff.x = sf.x - mean.x; diff.y = sf.y - mean.y;
    diff.z = sf.z - mean.z; diff.w = sf.w - mean.w;

    float* orow = out + (size_t)b * (2 * DIMS);
    *(float4*)(orow + lane * VEC)        = mean;
    *(float4*)(orow + DIMS + lane * VEC) = diff;
}

extern "C" void kernel_launch(void* const* d_in, const int* in_sizes, int n_in,
                              void* d_out, int out_size, void* d_ws, size_t ws_size,
                              hipStream_t stream) {
    const float* emb        = (const float*)d_in[0];
    const float* self_feats = (const float*)d_in[1];
    const int*   nidx       = (const int*)d_in[2];
    const int*   seg        = (const int*)d_in[3];
    float*       out        = (float*)d_out;

    const int B = in_sizes[1] / DIMS;   // self_feats is [B, 96]
    const int E = in_sizes[2];          // neighbor_idx length

    const int grid = (B + SEGS_PER_BLOCK - 1) / SEGS_PER_BLOCK;
    hipLaunchKernelGGL(seg_mean_concat_kernel, dim3(grid), dim3(THREADS), 0, stream,
                       emb, self_feats, nidx, seg, out, B, E);
}

// Round 5
// 62.071 us; speedup vs baseline: 1.3517x; 1.3517x over previous
//
#include <hip/hip_runtime.h>
#include <stdint.h>

#define DIMS 96
#define VEC 4
#define LANES (DIMS / VEC)        // 24 lanes cover one 96-dim row as float4
#define SEGS_PER_BLOCK 8
#define THREADS (LANES * SEGS_PER_BLOCK)  // 192 threads = 3 waves

// Round-5: fully de-serialized gather kernel.
//  - segment bounds precomputed by bounds_kernel into d_ws -> hot kernel has
//    NO barriers and NO LDS (round-4 regression showed barrier coupling costs
//    more than it buys).
//  - sched_group_barrier(VMEM_READ) pins 8 idx loads then 8 row gathers
//    back-to-back so all 8 dwordx4 gathers are genuinely in flight
//    (round-3 VGPR=32 proved the compiler batched them ~2-3 deep).
// NOTE: harness delivers integer inputs as int32.

__global__ __launch_bounds__(256) void bounds_kernel(
    const int* __restrict__ seg, int* __restrict__ bounds, int B, int E)
{
    const int t = blockIdx.x * blockDim.x + threadIdx.x;
    if (t > B) return;
    int lo = 0, hi = E;
    while (lo < hi) {
        const int mid = (lo + hi) >> 1;
        if (seg[mid] < t) lo = mid + 1; else hi = mid;
    }
    bounds[t] = lo;
}

__global__ __launch_bounds__(THREADS) void seg_mean_concat_kernel(
    const float* __restrict__ emb,        // [N, 96]
    const float* __restrict__ self_feats, // [B, 96]
    const int*   __restrict__ nidx,       // [E] int32
    const int*   __restrict__ seg,        // [E] int32, sorted
    const int*   __restrict__ bounds,     // [B+1] or nullptr
    float* __restrict__ out,              // [B, 192]
    int B, int E)
{
    const int tid  = threadIdx.x;
    const int g    = tid / LANES;
    const int lane = tid - g * LANES;
    const int b    = blockIdx.x * SEGS_PER_BLOCK + g;
    if (b >= B) return;

    int start, end;
    if (bounds) {
        start = bounds[b];
        end   = bounds[b + 1];
    } else {
        // fallback (ws too small): per-thread in-register search, still barrier-free
        int lo = 0, hi = E;
        while (lo < hi) { int m = (lo + hi) >> 1; if (seg[m] < b) lo = m + 1; else hi = m; }
        start = lo;
        hi = E;
        while (lo < hi) { int m = (lo + hi) >> 1; if (seg[m] < b + 1) lo = m + 1; else hi = m; }
        end = lo;
    }

    const float4* __restrict__ embv = (const float4*)emb;

    // issue early; consumed only in epilogue
    const float4 sf = *(const float4*)(self_feats + (size_t)b * DIMS + lane * VEC);

    float4 a0 = make_float4(0.f, 0.f, 0.f, 0.f);
    float4 a1 = make_float4(0.f, 0.f, 0.f, 0.f);

    int e = start;
    for (; e + 8 <= end; e += 8) {
        const int j0 = nidx[e + 0];
        const int j1 = nidx[e + 1];
        const int j2 = nidx[e + 2];
        const int j3 = nidx[e + 3];
        const int j4 = nidx[e + 4];
        const int j5 = nidx[e + 5];
        const int j6 = nidx[e + 6];
        const int j7 = nidx[e + 7];
        // cluster the 8 index loads
        __builtin_amdgcn_sched_group_barrier(0x20 /*VMEM_READ*/, 8, 0);
        const float4 v0 = embv[(size_t)j0 * LANES + lane];
        const float4 v1 = embv[(size_t)j1 * LANES + lane];
        const float4 v2 = embv[(size_t)j2 * LANES + lane];
        const float4 v3 = embv[(size_t)j3 * LANES + lane];
        const float4 v4 = embv[(size_t)j4 * LANES + lane];
        const float4 v5 = embv[(size_t)j5 * LANES + lane];
        const float4 v6 = embv[(size_t)j6 * LANES + lane];
        const float4 v7 = embv[(size_t)j7 * LANES + lane];
        // cluster the 8 row gathers back-to-back (all 8 in flight)
        __builtin_amdgcn_sched_group_barrier(0x20 /*VMEM_READ*/, 8, 0);
        a0.x += v0.x + v2.x + v4.x + v6.x;
        a0.y += v0.y + v2.y + v4.y + v6.y;
        a0.z += v0.z + v2.z + v4.z + v6.z;
        a0.w += v0.w + v2.w + v4.w + v6.w;
        a1.x += v1.x + v3.x + v5.x + v7.x;
        a1.y += v1.y + v3.y + v5.y + v7.y;
        a1.z += v1.z + v3.z + v5.z + v7.z;
        a1.w += v1.w + v3.w + v5.w + v7.w;
    }
    for (; e < end; ++e) {
        const int j = nidx[e];
        const float4 v = embv[(size_t)j * LANES + lane];
        a0.x += v.x; a0.y += v.y; a0.z += v.z; a0.w += v.w;
    }

    const int cnt = end - start;
    const float inv = 1.0f / (float)(cnt > 0 ? cnt : 1);
    float4 mean;
    mean.x = (a0.x + a1.x) * inv;
    mean.y = (a0.y + a1.y) * inv;
    mean.z = (a0.z + a1.z) * inv;
    mean.w = (a0.w + a1.w) * inv;

    float4 diff;
    diff.x = sf.x - mean.x; diff.y = sf.y - mean.y;
    diff.z = sf.z - mean.z; diff.w = sf.w - mean.w;

    float* orow = out + (size_t)b * (2 * DIMS);
    *(float4*)(orow + lane * VEC)        = mean;
    *(float4*)(orow + DIMS + lane * VEC) = diff;
}

extern "C" void kernel_launch(void* const* d_in, const int* in_sizes, int n_in,
                              void* d_out, int out_size, void* d_ws, size_t ws_size,
                              hipStream_t stream) {
    const float* emb        = (const float*)d_in[0];
    const float* self_feats = (const float*)d_in[1];
    const int*   nidx       = (const int*)d_in[2];
    const int*   seg        = (const int*)d_in[3];
    float*       out        = (float*)d_out;

    const int B = in_sizes[1] / DIMS;   // self_feats is [B, 96]
    const int E = in_sizes[2];          // neighbor_idx length

    int* bounds = nullptr;
    if (ws_size >= (size_t)(B + 1) * sizeof(int)) {
        bounds = (int*)d_ws;
        const int bgrid = (B + 1 + 255) / 256;
        hipLaunchKernelGGL(bounds_kernel, dim3(bgrid), dim3(256), 0, stream,
                           seg, bounds, B, E);
    }

    const int grid = (B + SEGS_PER_BLOCK - 1) / SEGS_PER_BLOCK;
    hipLaunchKernelGGL(seg_mean_concat_kernel, dim3(grid), dim3(THREADS), 0, stream,
                       emb, self_feats, nidx, seg, bounds, out, B, E);
}

// Round 6
// 60.428 us; speedup vs baseline: 1.3884x; 1.0272x over previous
//
#include <hip/hip_runtime.h>
#include <stdint.h>

#define DIMS 96
#define VEC 4
#define LANES (DIMS / VEC)        // 24 lanes cover one 96-dim row as float4
#define SEGS_PER_BLOCK 8
#define THREADS (LANES * SEGS_PER_BLOCK)  // 192 threads = 3 waves
#define UNROLL 8

// Round-6: keep round-5's barrier-free structure; deepen the pipeline.
//  - masked full-width iterations: tail slots clamp to end-1 (same-line dup
//    reads, ~free) and are masked out via 0/1-weight fma -> every segment is
//    processed at full 8-deep MLP (round-5's 1-deep remainder loop was the
//    biggest residual serial chain; avg segment = 16 edges).
//  - software-pipelined index prefetch: next iteration's 8 idx loads are
//    issued between the gathers and the accumulate, so they never sit on the
//    dependent path.
// NOTE: harness delivers integer inputs as int32.

__global__ __launch_bounds__(256) void bounds_kernel(
    const int* __restrict__ seg, int* __restrict__ bounds, int B, int E)
{
    const int t = blockIdx.x * blockDim.x + threadIdx.x;
    if (t > B) return;
    int lo = 0, hi = E;
    while (lo < hi) {
        const int mid = (lo + hi) >> 1;
        if (seg[mid] < t) lo = mid + 1; else hi = mid;
    }
    bounds[t] = lo;
}

__global__ __launch_bounds__(THREADS) void seg_mean_concat_kernel(
    const float* __restrict__ emb,        // [N, 96]
    const float* __restrict__ self_feats, // [B, 96]
    const int*   __restrict__ nidx,       // [E] int32
    const int*   __restrict__ seg,        // [E] int32, sorted
    const int*   __restrict__ bounds,     // [B+1] or nullptr
    float* __restrict__ out,              // [B, 192]
    int B, int E)
{
    const int tid  = threadIdx.x;
    const int g    = tid / LANES;
    const int lane = tid - g * LANES;
    const int b    = blockIdx.x * SEGS_PER_BLOCK + g;
    if (b >= B) return;

    int start, end;
    if (bounds) {
        start = bounds[b];
        end   = bounds[b + 1];
    } else {
        // fallback (ws too small): per-thread in-register search, barrier-free
        int lo = 0, hi = E;
        while (lo < hi) { int m = (lo + hi) >> 1; if (seg[m] < b) lo = m + 1; else hi = m; }
        start = lo;
        hi = E;
        while (lo < hi) { int m = (lo + hi) >> 1; if (seg[m] < b + 1) lo = m + 1; else hi = m; }
        end = lo;
    }

    const float4* __restrict__ embv = (const float4*)emb;

    // issued early; consumed only in epilogue
    const float4 sf = *(const float4*)(self_feats + (size_t)b * DIMS + lane * VEC);

    float4 a0 = make_float4(0.f, 0.f, 0.f, 0.f);
    float4 a1 = make_float4(0.f, 0.f, 0.f, 0.f);

    const int last = end - 1;
    if (start <= last) {
        int j[UNROLL];
        // prologue: first 8 clamped indices
#pragma unroll
        for (int k = 0; k < UNROLL; ++k) {
            int ee = start + k;
            ee = ee > last ? last : ee;
            j[k] = nidx[ee];
        }
        __builtin_amdgcn_sched_group_barrier(0x20 /*VMEM_READ*/, UNROLL, 0);

        for (int e = start; e <= last; e += UNROLL) {
            // issue 8 independent row gathers
            float4 v[UNROLL];
#pragma unroll
            for (int k = 0; k < UNROLL; ++k)
                v[k] = embv[(size_t)j[k] * LANES + lane];
            __builtin_amdgcn_sched_group_barrier(0x20 /*VMEM_READ*/, UNROLL, 0);

            // prefetch next iteration's indices (stay in flight through accum)
            const int en = e + UNROLL;
            if (en <= last) {
#pragma unroll
                for (int k = 0; k < UNROLL; ++k) {
                    int ee = en + k;
                    ee = ee > last ? last : ee;
                    j[k] = nidx[ee];
                }
                __builtin_amdgcn_sched_group_barrier(0x20 /*VMEM_READ*/, UNROLL, 0);
            }

            // masked accumulate (dual accumulators for VALU ILP)
#pragma unroll
            for (int k = 0; k < UNROLL; k += 2) {
                const float w0 = (e + k     <= last) ? 1.0f : 0.0f;
                const float w1 = (e + k + 1 <= last) ? 1.0f : 0.0f;
                a0.x = fmaf(v[k].x, w0, a0.x);
                a0.y = fmaf(v[k].y, w0, a0.y);
                a0.z = fmaf(v[k].z, w0, a0.z);
                a0.w = fmaf(v[k].w, w0, a0.w);
                a1.x = fmaf(v[k + 1].x, w1, a1.x);
                a1.y = fmaf(v[k + 1].y, w1, a1.y);
                a1.z = fmaf(v[k + 1].z, w1, a1.z);
                a1.w = fmaf(v[k + 1].w, w1, a1.w);
            }
        }
    }

    const int cnt = end - start;
    const float inv = 1.0f / (float)(cnt > 0 ? cnt : 1);
    float4 mean;
    mean.x = (a0.x + a1.x) * inv;
    mean.y = (a0.y + a1.y) * inv;
    mean.z = (a0.z + a1.z) * inv;
    mean.w = (a0.w + a1.w) * inv;

    float4 diff;
    diff.x = sf.x - mean.x; diff.y = sf.y - mean.y;
    diff.z = sf.z - mean.z; diff.w = sf.w - mean.w;

    float* orow = out + (size_t)b * (2 * DIMS);
    *(float4*)(orow + lane * VEC)        = mean;
    *(float4*)(orow + DIMS + lane * VEC) = diff;
}

extern "C" void kernel_launch(void* const* d_in, const int* in_sizes, int n_in,
                              void* d_out, int out_size, void* d_ws, size_t ws_size,
                              hipStream_t stream) {
    const float* emb        = (const float*)d_in[0];
    const float* self_feats = (const float*)d_in[1];
    const int*   nidx       = (const int*)d_in[2];
    const int*   seg        = (const int*)d_in[3];
    float*       out        = (float*)d_out;

    const int B = in_sizes[1] / DIMS;   // self_feats is [B, 96]
    const int E = in_sizes[2];          // neighbor_idx length

    int* bounds = nullptr;
    if (ws_size >= (size_t)(B + 1) * sizeof(int)) {
        bounds = (int*)d_ws;
        const int bgrid = (B + 1 + 255) / 256;
        hipLaunchKernelGGL(bounds_kernel, dim3(bgrid), dim3(256), 0, stream,
                           seg, bounds, B, E);
    }

    const int grid = (B + SEGS_PER_BLOCK - 1) / SEGS_PER_BLOCK;
    hipLaunchKernelGGL(seg_mean_concat_kernel, dim3(grid), dim3(THREADS), 0, stream,
                       emb, self_feats, nidx, seg, bounds, out, B, E);
}